// Round 1
// baseline (213.710 us; speedup 1.0000x reference)
//
#include <hip/hip_runtime.h>

// CountHistogram: B=64, C=4, Q=32, D=4096, NBINS=29
// out[b,c,q,bin] = sum_d mask[b,q,d] * (bin == trunc((simmat[b,c,q,d]+1.00001)/2*28))
//
// Layout: 1 block per (b,q); 4 waves/block, wave w handles c=w.
// Wave-private 29-bin LDS histogram -> no __syncthreads needed at all.
// float4/int4 coalesced loads; predicated LDS atomicAdd; lanes 0..28 store.

constexpr int Bdim  = 64;
constexpr int Cdim  = 4;
constexpr int Qdim  = 32;
constexpr int Ddim  = 4096;
constexpr int NBINS = 29;

__global__ __launch_bounds__(256, 8) void CountHistogram_33809982554604_kernel(
    const float* __restrict__ simmat,   // [B,C,Q,D] f32
    const int*   __restrict__ mask,     // [B,Q,D]   int32 (0/1)
    float*       __restrict__ out)      // [B,C,Q,NBINS] f32
{
    __shared__ unsigned int hist[4][32];   // [wave][bin], padded to 32

    const int bq   = blockIdx.x;          // 0 .. B*Q-1
    const int b    = bq >> 5;             // Q = 32
    const int q    = bq & 31;
    const int wave = threadIdx.x >> 6;    // = c
    const int lane = threadIdx.x & 63;

    if (lane < NBINS) hist[wave][lane] = 0u;
    // hist[wave] is touched only by this wave -> lockstep program order, no barrier.

    const float* __restrict__ srow =
        simmat + (((size_t)b * Cdim + wave) * Qdim + q) * Ddim;
    const int* __restrict__ mrow =
        mask + ((size_t)b * Qdim + q) * Ddim;

    #pragma unroll 4
    for (int j = 0; j < Ddim / 256; ++j) {      // 16 iterations
        const int idx = (j * 64 + lane) * 4;    // element index of this lane's float4
        const float4 x = *reinterpret_cast<const float4*>(srow + idx);
        const int4   m = *reinterpret_cast<const int4*>(mrow + idx);

        int b0 = (int)((x.x + 1.00001f) * 14.0f);
        int b1 = (int)((x.y + 1.00001f) * 14.0f);
        int b2 = (int)((x.z + 1.00001f) * 14.0f);
        int b3 = (int)((x.w + 1.00001f) * 14.0f);
        b0 = min(b0, NBINS - 1);
        b1 = min(b1, NBINS - 1);
        b2 = min(b2, NBINS - 1);
        b3 = min(b3, NBINS - 1);

        if (m.x) atomicAdd(&hist[wave][b0], 1u);
        if (m.y) atomicAdd(&hist[wave][b1], 1u);
        if (m.z) atomicAdd(&hist[wave][b2], 1u);
        if (m.w) atomicAdd(&hist[wave][b3], 1u);
    }

    if (lane < NBINS) {
        out[(((size_t)b * Cdim + wave) * Qdim + q) * NBINS + lane] =
            (float)hist[wave][lane];
    }
}

extern "C" void kernel_launch(void* const* d_in, const int* in_sizes, int n_in,
                              void* d_out, int out_size, void* d_ws, size_t ws_size,
                              hipStream_t stream) {
    const float* simmat = (const float*)d_in[0];
    const int*   mask   = (const int*)d_in[1];
    float*       out    = (float*)d_out;

    dim3 grid(Bdim * Qdim);   // 2048 blocks: one per (b,q)
    dim3 block(256);          // 4 waves: one per c
    CountHistogram_33809982554604_kernel<<<grid, block, 0, stream>>>(simmat, mask, out);
}

// Round 2
// 212.366 us; speedup vs baseline: 1.0063x; 1.0063x over previous
//
#include <hip/hip_runtime.h>

// CountHistogram: B=64, C=4, Q=32, D=4096, NBINS=29
// out[b,c,q,bin] = sum_d mask[b,q,d] * (bin == trunc((simmat[b,c,q,d]+1.00001)/2*28))
//
// R1: replace the 29-entry shared-per-wave LDS histogram (same-address atomic
// serialization, ~250 cyc/ds_add observed) with 32 replicated copies per wave:
// lane pair (2j,2j+1) owns copy j. Layout [bin][copy] (stride 32 words) puts
// copy j in bank j -> exactly 2 lanes/bank (free), same-address collision only
// when a pair draws the same bin (p=1/29). Fire-and-forget ds_add of m (0/1),
// no branches. 1 LDS instr/element -> LDS pipe ~5us/CU, under the ~25us HBM floor.

constexpr int Bdim  = 64;
constexpr int Cdim  = 4;
constexpr int Qdim  = 32;
constexpr int Ddim  = 4096;
constexpr int NBINS = 29;
constexpr int NCOPY = 32;                 // histogram replicas per wave
constexpr int WHIST = NBINS * NCOPY;      // 928 words per wave

__global__ __launch_bounds__(256) void CountHistogram_33809982554604_kernel(
    const float* __restrict__ simmat,   // [B,C,Q,D] f32
    const int*   __restrict__ mask,     // [B,Q,D]   int32 (0/1)
    float*       __restrict__ out)      // [B,C,Q,NBINS] f32
{
    __shared__ unsigned int hist[4][WHIST];   // 14848 B total

    const int bq   = blockIdx.x;          // 0 .. B*Q-1
    const int b    = bq >> 5;             // Q = 32
    const int q    = bq & 31;
    const int wave = threadIdx.x >> 6;    // = c
    const int lane = threadIdx.x & 63;
    const int copy = lane >> 1;           // lane pair -> replica

    unsigned int* __restrict__ h = hist[wave];

    // zero this wave's replicas (wave-private: lockstep, no barrier needed)
    for (int i = lane; i < WHIST; i += 64) h[i] = 0u;

    const float* __restrict__ srow =
        simmat + (((size_t)b * Cdim + wave) * Qdim + q) * Ddim;
    const int* __restrict__ mrow =
        mask + ((size_t)b * Qdim + q) * Ddim;

    #pragma unroll 4
    for (int j = 0; j < Ddim / 256; ++j) {      // 16 iterations
        const int idx = (j * 64 + lane) * 4;    // element index of this lane's float4
        const float4 x = *reinterpret_cast<const float4*>(srow + idx);
        const int4   m = *reinterpret_cast<const int4*>(mrow + idx);

        int b0 = (int)((x.x + 1.00001f) * 14.0f);
        int b1 = (int)((x.y + 1.00001f) * 14.0f);
        int b2 = (int)((x.z + 1.00001f) * 14.0f);
        int b3 = (int)((x.w + 1.00001f) * 14.0f);
        b0 = min(b0, NBINS - 1);
        b1 = min(b1, NBINS - 1);
        b2 = min(b2, NBINS - 1);
        b3 = min(b3, NBINS - 1);

        // fire-and-forget ds_add, no return, no branches; adds 0 for masked lanes
        atomicAdd(&h[b0 * NCOPY + copy], (unsigned int)m.x);
        atomicAdd(&h[b1 * NCOPY + copy], (unsigned int)m.y);
        atomicAdd(&h[b2 * NCOPY + copy], (unsigned int)m.z);
        atomicAdd(&h[b3 * NCOPY + copy], (unsigned int)m.w);
    }

    // reduce 32 replicas per bin; rotate column start so the 29 active lanes
    // hit 29 distinct banks each iteration
    if (lane < NBINS) {
        unsigned int sum = 0u;
        #pragma unroll
        for (int i = 0; i < NCOPY; ++i) {
            const int c = (lane + i) & (NCOPY - 1);
            sum += h[lane * NCOPY + c];
        }
        out[(((size_t)b * Cdim + wave) * Qdim + q) * NBINS + lane] = (float)sum;
    }
}

extern "C" void kernel_launch(void* const* d_in, const int* in_sizes, int n_in,
                              void* d_out, int out_size, void* d_ws, size_t ws_size,
                              hipStream_t stream) {
    const float* simmat = (const float*)d_in[0];
    const int*   mask   = (const int*)d_in[1];
    float*       out    = (float*)d_out;

    dim3 grid(Bdim * Qdim);   // 2048 blocks: one per (b,q)
    dim3 block(256);          // 4 waves: one per c
    CountHistogram_33809982554604_kernel<<<grid, block, 0, stream>>>(simmat, mask, out);
}

// Round 4
// 201.816 us; speedup vs baseline: 1.0589x; 1.0523x over previous
//
#include <hip/hip_runtime.h>

// CountHistogram: B=64, C=4, Q=32, D=4096, NBINS=29
// out[b,c,q,bin] = sum_d mask[b,q,d] * (bin == trunc((simmat[b,c,q,d]+1.00001)/2*28))
//
// R3 = R2 with the nontemporal builtin applied to native ext_vector_type(4)
// instead of HIP_vector_type (which the builtin rejects -> R2 compile fail).
// Structure: R1's replicated histogram (32 copies/wave, [bin][copy] layout,
// bank=copy -> 2 lanes/bank = free), nontemporal dwordx4 loads for the
// read-once simmat stream, unroll 8. Discriminating test vs fixed harness
// overhead: R0 (serialized ds_add) vs R1 (conflict-free) moved dur_us 0.6%;
// top-5 dispatches are 78us/512MiB harness poison fills. Kernel HBM floor:
// 160 MiB -> ~26us; dur_us carries ~170us+ of harness reset traffic.

constexpr int Bdim  = 64;
constexpr int Cdim  = 4;
constexpr int Qdim  = 32;
constexpr int Ddim  = 4096;
constexpr int NBINS = 29;
constexpr int NCOPY = 32;                 // histogram replicas per wave
constexpr int WHIST = NBINS * NCOPY;      // 928 words per wave

typedef float vf4 __attribute__((ext_vector_type(4)));
typedef int   vi4 __attribute__((ext_vector_type(4)));

__global__ __launch_bounds__(256) void CountHistogram_33809982554604_kernel(
    const float* __restrict__ simmat,   // [B,C,Q,D] f32
    const int*   __restrict__ mask,     // [B,Q,D]   int32 (0/1)
    float*       __restrict__ out)      // [B,C,Q,NBINS] f32
{
    __shared__ unsigned int hist[4][WHIST];   // 14848 B total

    const int bq   = blockIdx.x;          // 0 .. B*Q-1
    const int b    = bq >> 5;             // Q = 32
    const int q    = bq & 31;
    const int wave = threadIdx.x >> 6;    // = c
    const int lane = threadIdx.x & 63;
    const int copy = lane >> 1;           // lane pair -> replica

    unsigned int* __restrict__ h = hist[wave];

    // zero this wave's replicas (wave-private: lockstep, no barrier needed)
    for (int i = lane; i < WHIST; i += 64) h[i] = 0u;

    const float* __restrict__ srow =
        simmat + (((size_t)b * Cdim + wave) * Qdim + q) * Ddim;
    const int* __restrict__ mrow =
        mask + ((size_t)b * Qdim + q) * Ddim;

    #pragma unroll 8
    for (int j = 0; j < Ddim / 256; ++j) {      // 16 iterations
        const int idx = (j * 64 + lane) * 4;    // element index of this lane's float4
        const vf4 x = __builtin_nontemporal_load(
            reinterpret_cast<const vf4*>(srow + idx));
        const vi4 m = __builtin_nontemporal_load(
            reinterpret_cast<const vi4*>(mrow + idx));

        // (x+1.00001f)*14.0f is bit-identical to ((x+1.00001)/2)*28:
        // /2 is exact, single rounding on the *14 either way.
        int b0 = (int)((x.x + 1.00001f) * 14.0f);
        int b1 = (int)((x.y + 1.00001f) * 14.0f);
        int b2 = (int)((x.z + 1.00001f) * 14.0f);
        int b3 = (int)((x.w + 1.00001f) * 14.0f);
        b0 = min(b0, NBINS - 1);
        b1 = min(b1, NBINS - 1);
        b2 = min(b2, NBINS - 1);
        b3 = min(b3, NBINS - 1);

        // fire-and-forget ds_add, no return, no branches; adds 0 for masked lanes
        atomicAdd(&h[b0 * NCOPY + copy], (unsigned int)m.x);
        atomicAdd(&h[b1 * NCOPY + copy], (unsigned int)m.y);
        atomicAdd(&h[b2 * NCOPY + copy], (unsigned int)m.z);
        atomicAdd(&h[b3 * NCOPY + copy], (unsigned int)m.w);
    }

    // reduce 32 replicas per bin; rotate column start so the 29 active lanes
    // hit 29 distinct banks each iteration
    if (lane < NBINS) {
        unsigned int sum = 0u;
        #pragma unroll
        for (int i = 0; i < NCOPY; ++i) {
            const int c = (lane + i) & (NCOPY - 1);
            sum += h[lane * NCOPY + c];
        }
        out[(((size_t)b * Cdim + wave) * Qdim + q) * NBINS + lane] = (float)sum;
    }
}

extern "C" void kernel_launch(void* const* d_in, const int* in_sizes, int n_in,
                              void* d_out, int out_size, void* d_ws, size_t ws_size,
                              hipStream_t stream) {
    const float* simmat = (const float*)d_in[0];
    const int*   mask   = (const int*)d_in[1];
    float*       out    = (float*)d_out;

    dim3 grid(Bdim * Qdim);   // 2048 blocks: one per (b,q)
    dim3 block(256);          // 4 waves: one per c
    CountHistogram_33809982554604_kernel<<<grid, block, 0, stream>>>(simmat, mask, out);
}

// Round 5
// 201.207 us; speedup vs baseline: 1.0621x; 1.0030x over previous
//
#include <hip/hip_runtime.h>

// CountHistogram: B=64, C=4, Q=32, D=4096, NBINS=29
// out[b,c,q,bin] = sum_d mask[b,q,d] * (bin == trunc((simmat[b,c,q,d]+1.00001)/2*28))
//
// R4 = R3 with mask loads reverted to regular cached loads (single-variable
// test). simmat is read-once -> keep nontemporal. mask[b,q,:] is read by all
// 4 waves of the block -> NT defeats the x4 L1/L2 reuse and can inflate mask
// HBM traffic 32->128 MiB (+15us on a ~26us floor). Histogram structure
// unchanged from R1: 32 replicas/wave, [bin][copy] layout, bank=copy ->
// 2 lanes/bank (free tier per m136), fire-and-forget ds_add, no branches.

constexpr int Bdim  = 64;
constexpr int Cdim  = 4;
constexpr int Qdim  = 32;
constexpr int Ddim  = 4096;
constexpr int NBINS = 29;
constexpr int NCOPY = 32;                 // histogram replicas per wave
constexpr int WHIST = NBINS * NCOPY;      // 928 words per wave

typedef float vf4 __attribute__((ext_vector_type(4)));
typedef int   vi4 __attribute__((ext_vector_type(4)));

__global__ __launch_bounds__(256) void CountHistogram_33809982554604_kernel(
    const float* __restrict__ simmat,   // [B,C,Q,D] f32
    const int*   __restrict__ mask,     // [B,Q,D]   int32 (0/1)
    float*       __restrict__ out)      // [B,C,Q,NBINS] f32
{
    __shared__ unsigned int hist[4][WHIST];   // 14848 B total

    const int bq   = blockIdx.x;          // 0 .. B*Q-1
    const int b    = bq >> 5;             // Q = 32
    const int q    = bq & 31;
    const int wave = threadIdx.x >> 6;    // = c
    const int lane = threadIdx.x & 63;
    const int copy = lane >> 1;           // lane pair -> replica

    unsigned int* __restrict__ h = hist[wave];

    // zero this wave's replicas (wave-private: lockstep, no barrier needed)
    for (int i = lane; i < WHIST; i += 64) h[i] = 0u;

    const float* __restrict__ srow =
        simmat + (((size_t)b * Cdim + wave) * Qdim + q) * Ddim;
    const int* __restrict__ mrow =
        mask + ((size_t)b * Qdim + q) * Ddim;

    #pragma unroll 8
    for (int j = 0; j < Ddim / 256; ++j) {      // 16 iterations
        const int idx = (j * 64 + lane) * 4;    // element index of this lane's float4
        // simmat: read-once stream -> nontemporal
        const vf4 x = __builtin_nontemporal_load(
            reinterpret_cast<const vf4*>(srow + idx));
        // mask: reused by all 4 waves of this block -> normal cached load
        const vi4 m = *reinterpret_cast<const vi4*>(mrow + idx);

        // (x+1.00001f)*14.0f is bit-identical to ((x+1.00001)/2)*28:
        // /2 is exact, single rounding on the *14 either way.
        int b0 = (int)((x.x + 1.00001f) * 14.0f);
        int b1 = (int)((x.y + 1.00001f) * 14.0f);
        int b2 = (int)((x.z + 1.00001f) * 14.0f);
        int b3 = (int)((x.w + 1.00001f) * 14.0f);
        b0 = min(b0, NBINS - 1);
        b1 = min(b1, NBINS - 1);
        b2 = min(b2, NBINS - 1);
        b3 = min(b3, NBINS - 1);

        // fire-and-forget ds_add, no return, no branches; adds 0 for masked lanes
        atomicAdd(&h[b0 * NCOPY + copy], (unsigned int)m.x);
        atomicAdd(&h[b1 * NCOPY + copy], (unsigned int)m.y);
        atomicAdd(&h[b2 * NCOPY + copy], (unsigned int)m.z);
        atomicAdd(&h[b3 * NCOPY + copy], (unsigned int)m.w);
    }

    // reduce 32 replicas per bin; rotate column start so the 29 active lanes
    // hit 29 distinct banks each iteration
    if (lane < NBINS) {
        unsigned int sum = 0u;
        #pragma unroll
        for (int i = 0; i < NCOPY; ++i) {
            const int c = (lane + i) & (NCOPY - 1);
            sum += h[lane * NCOPY + c];
        }
        out[(((size_t)b * Cdim + wave) * Qdim + q) * NBINS + lane] = (float)sum;
    }
}

extern "C" void kernel_launch(void* const* d_in, const int* in_sizes, int n_in,
                              void* d_out, int out_size, void* d_ws, size_t ws_size,
                              hipStream_t stream) {
    const float* simmat = (const float*)d_in[0];
    const int*   mask   = (const int*)d_in[1];
    float*       out    = (float*)d_out;

    dim3 grid(Bdim * Qdim);   // 2048 blocks: one per (b,q)
    dim3 block(256);          // 4 waves: one per c
    CountHistogram_33809982554604_kernel<<<grid, block, 0, stream>>>(simmat, mask, out);
}

// Round 6
// 200.386 us; speedup vs baseline: 1.0665x; 1.0041x over previous
//
#include <hip/hip_runtime.h>

// CountHistogram: B=64, C=4, Q=32, D=4096, NBINS=29
// out[b,c,q,bin] = sum_d mask[b,q,d] * (bin == trunc((simmat[b,c,q,d]+1.00001)/2*28))
//
// R5: discriminating probe of LDS-atomic base throughput. R0 (serialized
// same-address ds_add) vs R2 (conflict-free replicated ds_add) differed by
// only 1.3us -> either atomics never mattered, or the atomic RMW unit's base
// lane throughput bottlenecks both equally (~27-55us at 1-2 lanes/cyc for
// 131K lane-atomics/CU — exactly the ~45us kernel slack over the 26us HBM
// floor). This version removes atomics entirely: NCOPY=64, each lane owns
// column `lane` -> plain ds_read + v_add + ds_write (no aliasing within the
// wave, hist is wave-private, per-lane RMW is program-ordered). Bank =
// lane&31 -> 2 lanes/bank on distinct dwords = free tier (m136).
// LDS 29,696 B/block -> 5 blocks/CU (20 waves/CU, still latency-covered).
// Kept from R3/R4: nontemporal simmat stream, cached mask, unroll 8.

constexpr int Bdim  = 64;
constexpr int Cdim  = 4;
constexpr int Qdim  = 32;
constexpr int Ddim  = 4096;
constexpr int NBINS = 29;
constexpr int NCOPY = 64;                 // one private column per lane
constexpr int WHIST = NBINS * NCOPY;      // 1856 words per wave

typedef float vf4 __attribute__((ext_vector_type(4)));
typedef int   vi4 __attribute__((ext_vector_type(4)));

__global__ __launch_bounds__(256) void CountHistogram_33809982554604_kernel(
    const float* __restrict__ simmat,   // [B,C,Q,D] f32
    const int*   __restrict__ mask,     // [B,Q,D]   int32 (0/1)
    float*       __restrict__ out)      // [B,C,Q,NBINS] f32
{
    __shared__ unsigned int hist[4][WHIST];   // 29,696 B total

    const int bq   = blockIdx.x;          // 0 .. B*Q-1
    const int b    = bq >> 5;             // Q = 32
    const int q    = bq & 31;
    const int wave = threadIdx.x >> 6;    // = c
    const int lane = threadIdx.x & 63;

    unsigned int* __restrict__ h = hist[wave];

    // zero this wave's private columns (wave-private: lockstep, no barrier)
    for (int i = lane; i < WHIST; i += 64) h[i] = 0u;

    const float* __restrict__ srow =
        simmat + (((size_t)b * Cdim + wave) * Qdim + q) * Ddim;
    const int* __restrict__ mrow =
        mask + ((size_t)b * Qdim + q) * Ddim;

    #pragma unroll 8
    for (int j = 0; j < Ddim / 256; ++j) {      // 16 iterations
        const int idx = (j * 64 + lane) * 4;    // element index of this lane's float4
        // simmat: read-once stream -> nontemporal
        const vf4 x = __builtin_nontemporal_load(
            reinterpret_cast<const vf4*>(srow + idx));
        // mask: reused by all 4 waves of this block -> normal cached load
        const vi4 m = *reinterpret_cast<const vi4*>(mrow + idx);

        // (x+1.00001f)*14.0f is bit-identical to ((x+1.00001)/2)*28:
        // /2 is exact, single rounding on the *14 either way.
        int b0 = (int)((x.x + 1.00001f) * 14.0f);
        int b1 = (int)((x.y + 1.00001f) * 14.0f);
        int b2 = (int)((x.z + 1.00001f) * 14.0f);
        int b3 = (int)((x.w + 1.00001f) * 14.0f);
        b0 = min(b0, NBINS - 1);
        b1 = min(b1, NBINS - 1);
        b2 = min(b2, NBINS - 1);
        b3 = min(b3, NBINS - 1);

        // non-atomic privatized RMW: lane owns column `lane`, no aliasing
        h[b0 * NCOPY + lane] += (unsigned int)m.x;
        h[b1 * NCOPY + lane] += (unsigned int)m.y;
        h[b2 * NCOPY + lane] += (unsigned int)m.z;
        h[b3 * NCOPY + lane] += (unsigned int)m.w;
    }

    // reduce 64 private columns per bin; rotate column start so lanes spread
    // across banks each iteration
    if (lane < NBINS) {
        unsigned int sum = 0u;
        #pragma unroll
        for (int i = 0; i < NCOPY; ++i) {
            const int c = (lane + i) & (NCOPY - 1);
            sum += h[lane * NCOPY + c];
        }
        out[(((size_t)b * Cdim + wave) * Qdim + q) * NBINS + lane] = (float)sum;
    }
}

extern "C" void kernel_launch(void* const* d_in, const int* in_sizes, int n_in,
                              void* d_out, int out_size, void* d_ws, size_t ws_size,
                              hipStream_t stream) {
    const float* simmat = (const float*)d_in[0];
    const int*   mask   = (const int*)d_in[1];
    float*       out    = (float*)d_out;

    dim3 grid(Bdim * Qdim);   // 2048 blocks: one per (b,q)
    dim3 block(256);          // 4 waves: one per c
    CountHistogram_33809982554604_kernel<<<grid, block, 0, stream>>>(simmat, mask, out);
}